// Round 1
// baseline (675.908 us; speedup 1.0000x reference)
//
#include <hip/hip_runtime.h>
#include <stdint.h>

#define N_ANCH 250000
#define N_CLS 81
#define K_TOP 200
#define SORT_N 4096
#define IOU_THR 0.45f
#define SCORE_THR 0.01f

typedef unsigned long long u64;

// ---------------- Kernel 1: per-anchor max/argmax over classes 1..80 --------
// One wave (64 lanes) per anchor; row is 81 contiguous floats.
// Key = (score_bits << 32) | ~anchor  -> descending key order == (score desc, anchor asc),
// exactly matching lax.top_k tie-breaking (lower index first on equal score).
__global__ void score_reduce(const float* __restrict__ scores,
                             u64* __restrict__ keys, int* __restrict__ labels) {
  int wave = blockIdx.x * (blockDim.x >> 6) + (threadIdx.x >> 6);
  int lane = threadIdx.x & 63;
  if (wave >= N_ANCH) return;
  const float* row = scores + (long long)wave * N_CLS;
  float v = row[1 + lane];          // fg class index = lane (0..63)
  int c = lane;
  if (lane < 16) {
    float v2 = row[65 + lane];      // fg class index = 64+lane (64..79)
    if (v2 > v) { v = v2; c = 64 + lane; }   // tie -> keep smaller index (first occurrence)
  }
  for (int off = 32; off > 0; off >>= 1) {
    float ov = __shfl_down(v, off, 64);
    int   oc = __shfl_down(c, off, 64);
    if (ov > v || (ov == v && oc < c)) { v = ov; c = oc; }
  }
  if (lane == 0) {
    keys[wave] = ((u64)__float_as_uint(v) << 32) | (unsigned)(~(unsigned)wave);
    labels[wave] = c;
  }
}

// ---------------- Kernel 2: block-local bitonic sort (descending), emit top-200
// Each block sorts a 4096-key chunk in LDS and writes its top 200 keys.
// Selection-safe: any element of the global top-200 is in its chunk's top-200.
__global__ void topk_sort(const u64* __restrict__ in, int n, u64* __restrict__ out) {
  __shared__ u64 s[SORT_N];
  int tid = threadIdx.x;
  long long base = (long long)blockIdx.x * SORT_N;
  for (int i = tid; i < SORT_N; i += blockDim.x) {
    long long g = base + i;
    s[i] = (g < n) ? in[g] : 0ULL;   // pad with 0 < any real key (low 32 bits hold ~idx)
  }
  __syncthreads();
  for (int k = 2; k <= SORT_N; k <<= 1) {
    for (int j = k >> 1; j > 0; j >>= 1) {
      for (int i = tid; i < SORT_N; i += blockDim.x) {
        int ixj = i ^ j;
        if (ixj > i) {
          u64 a = s[i], b = s[ixj];
          bool desc = ((i & k) == 0);           // descending overall at k == SORT_N
          bool sw = desc ? (a < b) : (a > b);
          if (sw) { s[i] = b; s[ixj] = a; }
        }
      }
      __syncthreads();
    }
  }
  for (int t = tid; t < K_TOP; t += blockDim.x)
    out[(long long)blockIdx.x * K_TOP + t] = s[t];
}

// ---------------- Kernel 3: decode top-200, greedy NMS, write outputs -------
__global__ void nms_out(const u64* __restrict__ topk, const int* __restrict__ labels,
                        const float* __restrict__ boxes,
                        const int* __restrict__ wptr, const int* __restrict__ hptr,
                        float* __restrict__ out) {
  __shared__ float sx1[K_TOP], sy1[K_TOP], sx2[K_TOP], sy2[K_TOP], sarea[K_TOP];
  __shared__ float red[256];
  __shared__ u64 rows[K_TOP * 4];   // suppression bitmask rows (j > i, iou > thr)
  __shared__ u64 keepw[4];
  int t = threadIdx.x;
  float score = 0.f, b0 = 0.f, b1 = 0.f, b2 = 0.f, b3 = 0.f;
  int lab = 0;
  if (t < K_TOP) {
    u64 key = topk[t];
    score = __uint_as_float((unsigned)(key >> 32));
    unsigned anchor = ~(unsigned)(key & 0xFFFFFFFFULL);
    lab = labels[anchor];
    const float* bp = boxes + (long long)anchor * 4;
    b0 = bp[0]; b1 = bp[1]; b2 = bp[2]; b3 = bp[3];
  }
  // max_coord over ALL 200 boxes (reference does not condition on valid)
  red[t] = (t < K_TOP) ? fmaxf(fmaxf(b0, b1), fmaxf(b2, b3)) : -1e30f;
  __syncthreads();
  for (int s = 128; s > 0; s >>= 1) {
    if (t < s) red[t] = fmaxf(red[t], red[t + s]);
    __syncthreads();
  }
  float max_coord = red[0];
  if (t < K_TOP) {
    float off = (float)lab * (max_coord + 1.0f);
    float x1 = b0 + off, y1 = b1 + off, x2 = b2 + off, y2 = b3 + off;
    sx1[t] = x1; sy1[t] = y1; sx2[t] = x2; sy2[t] = y2;
    // area from SHIFTED coords, matching reference op order exactly
    sarea[t] = fmaxf(x2 - x1, 0.f) * fmaxf(y2 - y1, 0.f);
  }
  __syncthreads();
  // Build suppression rows: task = i*4 + word; lane l covers j = word*64 + l
  int wv = t >> 6, l = t & 63;
  for (int task = wv; task < K_TOP * 4; task += 4) {
    int i = task >> 2, w = task & 3;
    int j = (w << 6) + l;
    bool pred = false;
    if (j < K_TOP && j > i) {
      float xx1 = fmaxf(sx1[i], sx1[j]);
      float yy1 = fmaxf(sy1[i], sy1[j]);
      float xx2 = fminf(sx2[i], sx2[j]);
      float yy2 = fminf(sy2[i], sy2[j]);
      float inter = fmaxf(xx2 - xx1, 0.f) * fmaxf(yy2 - yy1, 0.f);
      float uni = sarea[i] + sarea[j] - inter;
      float iou = inter / fmaxf(uni, 1e-12f);
      pred = iou > IOU_THR;
    }
    u64 mask = __ballot(pred);
    if (l == 0) rows[task] = mask;
  }
  // initial keep = valid mask
  bool valid = (t < K_TOP) && (score > SCORE_THR);
  u64 vm = __ballot(valid);
  if (l == 0) keepw[wv] = vm;
  __syncthreads();
  if (t == 0) {
    u64 K0 = keepw[0], K1 = keepw[1], K2 = keepw[2], K3 = keepw[3];
    for (int i = 0; i < K_TOP; i++) {
      u64 word = (i < 64) ? K0 : (i < 128) ? K1 : (i < 192) ? K2 : K3;
      if ((word >> (i & 63)) & 1ULL) {
        K0 &= ~rows[i * 4 + 0];
        K1 &= ~rows[i * 4 + 1];
        K2 &= ~rows[i * 4 + 2];
        K3 &= ~rows[i * 4 + 3];
      }
    }
    keepw[0] = K0; keepw[1] = K1; keepw[2] = K2; keepw[3] = K3;
  }
  __syncthreads();
  if (t < K_TOP) {
    bool keep = (keepw[t >> 6] >> (t & 63)) & 1ULL;
    float sw = (float)(*wptr), sh = (float)(*hptr);
    out[t * 4 + 0] = keep ? b0 * sw : 0.f;
    out[t * 4 + 1] = keep ? b1 * sh : 0.f;
    out[t * 4 + 2] = keep ? b2 * sw : 0.f;
    out[t * 4 + 3] = keep ? b3 * sh : 0.f;
    out[4 * K_TOP + t] = keep ? (float)(lab + 1) : 0.f;
    out[5 * K_TOP + t] = keep ? score : 0.f;
  }
}

extern "C" void kernel_launch(void* const* d_in, const int* in_sizes, int n_in,
                              void* d_out, int out_size, void* d_ws, size_t ws_size,
                              hipStream_t stream) {
  const float* scores = (const float*)d_in[0];
  const float* boxes  = (const float*)d_in[1];
  const int* wptr = (const int*)d_in[2];
  const int* hptr = (const int*)d_in[3];
  float* out = (float*)d_out;

  char* ws = (char*)d_ws;
  u64* keys   = (u64*)(ws);                       // 250000 * 8 = 2,000,000 B
  int* labels = (int*)(ws + 2000000);             // 250000 * 4 = 1,000,000 B
  u64* buf1   = (u64*)(ws + 3000000);             // 12400 * 8  =    99,200 B
  u64* buf2   = (u64*)(ws + 3099200);             //   800 * 8  =     6,400 B
  u64* buf3   = (u64*)(ws + 3105600);             //   200 * 8  =     1,600 B

  // 1) per-anchor class reduce: 4 waves/block, 1 anchor/wave
  score_reduce<<<(N_ANCH + 3) / 4, 256, 0, stream>>>(scores, keys, labels);

  // 2) hierarchical top-200: 250000 -> 12400 -> 800 -> 200 (sorted desc)
  int b1 = (N_ANCH + SORT_N - 1) / SORT_N;        // 62
  topk_sort<<<b1, 256, 0, stream>>>(keys, N_ANCH, buf1);
  int n2 = b1 * K_TOP;                            // 12400
  int b2 = (n2 + SORT_N - 1) / SORT_N;            // 4
  topk_sort<<<b2, 256, 0, stream>>>(buf1, n2, buf2);
  int n3 = b2 * K_TOP;                            // 800
  topk_sort<<<1, 256, 0, stream>>>(buf2, n3, buf3);

  // 3) NMS + outputs (single block)
  nms_out<<<1, 256, 0, stream>>>(buf3, labels, boxes, wptr, hptr, out);
}

// Round 2
// 294.866 us; speedup vs baseline: 2.2923x; 2.2923x over previous
//
#include <hip/hip_runtime.h>
#include <stdint.h>

#define N_ANCH 250000
#define N_CLS 81
#define K_TOP 200
#define CAP 2048
#define IOU_THR 0.45f
#define SCORE_THR 0.01f

typedef unsigned long long u64;
typedef unsigned int u32;

// ws layout (bytes):
//   histA  [0, 1024)        256 u32   (bits 31:24)
//   histB  [1024, 2048)     256 u32   (bits 23:16)
//   histC  [2048, 18432)    4096 u32  (bits 15:4)
//   state  [18432, 18464)   8 u32: 0=b0 1=K1 2=b1 3=K2 4=w12 5=K3 6=counter
//   -- memset zero region: [0, 18464) --
//   keys32 [32768, 32768+1000000)
//   cand   [1048576, +CAP*8)

// ---- Kernel 1: per-anchor max over fg classes -> keys32, + 256-bin LDS hist
// One wave per anchor (64 iterations per wave), block = 256 anchors.
__global__ void score_reduce(const float* __restrict__ scores,
                             u32* __restrict__ keys, u32* __restrict__ histA) {
  __shared__ u32 lh[256];
  __shared__ u32 kbuf[4][64];
  int t = threadIdx.x;
  lh[t] = 0;
  int wv = t >> 6, lane = t & 63;
  __syncthreads();
  int base = blockIdx.x * 256 + wv * 64;
  for (int it = 0; it < 64; ++it) {
    int a = base + it;
    float v = -1.f; int c = 0;
    if (a < N_ANCH) {
      const float* row = scores + (long long)a * N_CLS;
      v = row[1 + lane]; c = lane;
      if (lane < 16) {
        float v2 = row[65 + lane];
        if (v2 > v) { v = v2; c = 64 + lane; }   // tie -> first occurrence
      }
    }
    for (int off = 32; off > 0; off >>= 1) {
      float ov = __shfl_down(v, off, 64);
      int   oc = __shfl_down(c, off, 64);
      if (ov > v || (ov == v && oc < c)) { v = ov; c = oc; }
    }
    if (lane == 0 && a < N_ANCH) {
      u32 kb = __float_as_uint(v);
      kbuf[wv][it] = kb;
      atomicAdd(&lh[kb >> 24], 1u);
    }
  }
  __syncthreads();
  int a = blockIdx.x * 256 + wv * 64 + lane;
  if (a < N_ANCH) keys[a] = kbuf[wv][lane];   // coalesced key write
  if (lh[t]) atomicAdd(&histA[t], lh[t]);     // few occupied bins per block
}

// ---- Generic suffix-scan over a histogram: find smallest bin b with
// count(>= b) >= K; outputs b and K' = K - count(> b).
__global__ void scan_hist(const u32* __restrict__ hist, int nbins,
                          const u32* __restrict__ Kin, u32 Kimm,
                          u32* __restrict__ b_out, u32* __restrict__ K_out) {
  __shared__ u32 csum[256];
  __shared__ u32 suf[256];
  int t = threadIdx.x;
  int chunk = nbins >> 8;
  int base = t * chunk;
  u32 s = 0;
  for (int i = 0; i < chunk; ++i) s += hist[base + i];
  csum[t] = s;
  __syncthreads();
  if (t == 0) {
    u32 acc = 0;
    for (int i = 255; i >= 0; --i) { suf[i] = acc; acc += csum[i]; }
  }
  __syncthreads();
  u32 K = Kin ? *Kin : Kimm;
  if (suf[t] < K && suf[t] + csum[t] >= K) {   // unique owner
    u32 acc = suf[t];
    for (int i = chunk - 1; i >= 0; --i) {
      u32 c = hist[base + i];
      if (acc + c >= K) { *b_out = (u32)(base + i); *K_out = K - acc; break; }
      acc += c;
    }
  }
}

// ---- Pass 2 histogram: bits [23:16] among keys whose top byte == b0
__global__ void hist_b(const u32* __restrict__ keys, const u32* __restrict__ state,
                       u32* __restrict__ histB) {
  __shared__ u32 lh[256];
  int t = threadIdx.x;
  lh[t] = 0; __syncthreads();
  int i = blockIdx.x * 256 + t;
  u32 b0 = state[0];
  if (i < N_ANCH) {
    u32 k = keys[i];
    if ((k >> 24) == b0) atomicAdd(&lh[(k >> 16) & 0xFFu], 1u);
  }
  __syncthreads();
  if (lh[t]) atomicAdd(&histB[t], lh[t]);
}

// ---- Pass 3 histogram: bits [15:4] (4096 bins) among keys matching top-16 prefix
__global__ void hist_c(const u32* __restrict__ keys, const u32* __restrict__ state,
                       u32* __restrict__ histC) {
  int i = blockIdx.x * 256 + threadIdx.x;
  if (i >= N_ANCH) return;
  u32 pre = (state[0] << 8) | state[2];
  u32 k = keys[i];
  if ((k >> 16) == pre) atomicAdd(&histC[(k >> 4) & 0xFFFu], 1u);
}

// ---- Compact all keys >= threshold into candidate buffer (u64 tie-exact keys)
__global__ void compact(const u32* __restrict__ keys, u32* __restrict__ state,
                        u64* __restrict__ cand) {
  int i = blockIdx.x * 256 + threadIdx.x;
  if (i >= N_ANCH) return;
  u32 T = (state[0] << 24) | (state[2] << 16) | (state[4] << 4);
  u32 k = keys[i];
  if (k >= T) {
    u32 pos = atomicAdd(&state[6], 1u);
    if (pos < CAP) cand[pos] = ((u64)k << 32) | (u32)(~(u32)i);
  }
}

// ---- Final: exact rank of candidates -> top-200 in order, then greedy NMS
__global__ void final_nms(const u64* __restrict__ cand_g, const u32* __restrict__ state,
                          const float* __restrict__ scores, const float* __restrict__ boxes,
                          const int* __restrict__ wptr, const int* __restrict__ hptr,
                          float* __restrict__ out) {
  __shared__ u64 cand[CAP];
  __shared__ u32 s_anchor[K_TOP];
  __shared__ float s_score[K_TOP];
  __shared__ float sx1[K_TOP], sy1[K_TOP], sx2[K_TOP], sy2[K_TOP], sarea[K_TOP];
  __shared__ float red[256];
  __shared__ u64 rows[K_TOP * 4];
  __shared__ u64 keepw[4];
  int t = threadIdx.x;
  int M = (int)state[6]; if (M > CAP) M = CAP;
  for (int i = t; i < M; i += 256) cand[i] = cand_g[i];
  if (t < K_TOP) { s_anchor[t] = 0u; s_score[t] = 0.f; }
  __syncthreads();
  // exact rank: keys unique (low bits ~idx) -> unique ranks; rank<200 = top-200
  for (int i = t; i < M; i += 256) {
    u64 k = cand[i]; int r = 0;
    for (int j = 0; j < M; ++j) r += (cand[j] > k) ? 1 : 0;
    if (r < K_TOP) {
      s_anchor[r] = ~(u32)(k & 0xFFFFFFFFULL);
      s_score[r] = __uint_as_float((u32)(k >> 32));
    }
  }
  __syncthreads();
  float score = 0.f, b0 = 0.f, b1 = 0.f, b2 = 0.f, b3 = 0.f;
  int lab = 0;
  if (t < K_TOP) {
    score = s_score[t];
    u32 a = s_anchor[t];
    const float* bp = boxes + (long long)a * 4;
    b0 = bp[0]; b1 = bp[1]; b2 = bp[2]; b3 = bp[3];
    // recompute first-occurrence argmax over fg classes for this anchor
    const float* row = scores + (long long)a * N_CLS;
    float best = row[1]; lab = 0;
    for (int c = 2; c <= 80; ++c) {
      float v = row[c];
      if (v > best) { best = v; lab = c - 1; }
    }
  }
  // max_coord over ALL 200 boxes
  red[t] = (t < K_TOP) ? fmaxf(fmaxf(b0, b1), fmaxf(b2, b3)) : -1e30f;
  __syncthreads();
  for (int s = 128; s > 0; s >>= 1) {
    if (t < s) red[t] = fmaxf(red[t], red[t + s]);
    __syncthreads();
  }
  float max_coord = red[0];
  if (t < K_TOP) {
    float off = (float)lab * (max_coord + 1.0f);
    float x1 = b0 + off, y1 = b1 + off, x2 = b2 + off, y2 = b3 + off;
    sx1[t] = x1; sy1[t] = y1; sx2[t] = x2; sy2[t] = y2;
    sarea[t] = fmaxf(x2 - x1, 0.f) * fmaxf(y2 - y1, 0.f);
  }
  __syncthreads();
  int wv = t >> 6, l = t & 63;
  for (int task = wv; task < K_TOP * 4; task += 4) {
    int i = task >> 2, w = task & 3;
    int j = (w << 6) + l;
    bool pred = false;
    if (j < K_TOP && j > i) {
      float xx1 = fmaxf(sx1[i], sx1[j]);
      float yy1 = fmaxf(sy1[i], sy1[j]);
      float xx2 = fminf(sx2[i], sx2[j]);
      float yy2 = fminf(sy2[i], sy2[j]);
      float inter = fmaxf(xx2 - xx1, 0.f) * fmaxf(yy2 - yy1, 0.f);
      float uni = sarea[i] + sarea[j] - inter;
      float iou = inter / fmaxf(uni, 1e-12f);
      pred = iou > IOU_THR;
    }
    u64 mask = __ballot(pred);
    if (l == 0) rows[task] = mask;
  }
  bool valid = (t < K_TOP) && (score > SCORE_THR);
  u64 vm = __ballot(valid);
  if (l == 0) keepw[wv] = vm;
  __syncthreads();
  if (t == 0) {
    u64 K0 = keepw[0], K1 = keepw[1], K2 = keepw[2], K3 = keepw[3];
    for (int i = 0; i < K_TOP; i++) {
      u64 word = (i < 64) ? K0 : (i < 128) ? K1 : (i < 192) ? K2 : K3;
      if ((word >> (i & 63)) & 1ULL) {
        K0 &= ~rows[i * 4 + 0];
        K1 &= ~rows[i * 4 + 1];
        K2 &= ~rows[i * 4 + 2];
        K3 &= ~rows[i * 4 + 3];
      }
    }
    keepw[0] = K0; keepw[1] = K1; keepw[2] = K2; keepw[3] = K3;
  }
  __syncthreads();
  if (t < K_TOP) {
    bool keep = (keepw[t >> 6] >> (t & 63)) & 1ULL;
    float sw = (float)(*wptr), sh = (float)(*hptr);
    out[t * 4 + 0] = keep ? b0 * sw : 0.f;
    out[t * 4 + 1] = keep ? b1 * sh : 0.f;
    out[t * 4 + 2] = keep ? b2 * sw : 0.f;
    out[t * 4 + 3] = keep ? b3 * sh : 0.f;
    out[4 * K_TOP + t] = keep ? (float)(lab + 1) : 0.f;
    out[5 * K_TOP + t] = keep ? score : 0.f;
  }
}

extern "C" void kernel_launch(void* const* d_in, const int* in_sizes, int n_in,
                              void* d_out, int out_size, void* d_ws, size_t ws_size,
                              hipStream_t stream) {
  const float* scores = (const float*)d_in[0];
  const float* boxes  = (const float*)d_in[1];
  const int* wptr = (const int*)d_in[2];
  const int* hptr = (const int*)d_in[3];
  float* out = (float*)d_out;

  char* ws = (char*)d_ws;
  u32* histA = (u32*)(ws + 0);
  u32* histB = (u32*)(ws + 1024);
  u32* histC = (u32*)(ws + 2048);
  u32* state = (u32*)(ws + 18432);
  u32* keys  = (u32*)(ws + 32768);
  u64* cand  = (u64*)(ws + 1048576);

  hipMemsetAsync(ws, 0, 18464, stream);

  int blocks = (N_ANCH + 255) / 256;   // 977

  score_reduce<<<blocks, 256, 0, stream>>>(scores, keys, histA);
  scan_hist<<<1, 256, 0, stream>>>(histA, 256, nullptr, 200, &state[0], &state[1]);
  hist_b<<<blocks, 256, 0, stream>>>(keys, state, histB);
  scan_hist<<<1, 256, 0, stream>>>(histB, 256, &state[1], 0, &state[2], &state[3]);
  hist_c<<<blocks, 256, 0, stream>>>(keys, state, histC);
  scan_hist<<<1, 256, 0, stream>>>(histC, 4096, &state[3], 0, &state[4], &state[5]);
  compact<<<blocks, 256, 0, stream>>>(keys, state, cand);
  final_nms<<<1, 256, 0, stream>>>(cand, state, scores, boxes, wptr, hptr, out);
}

// Round 3
// 288.909 us; speedup vs baseline: 2.3395x; 1.0206x over previous
//
#include <hip/hip_runtime.h>
#include <stdint.h>

#define N_ANCH 250000
#define N_CLS 81
#define K_TOP 200
#define CAP 4096
#define NBINS 4096
#define IOU_THR 0.45f
#define SCORE_THR 0.01f

typedef unsigned long long u64;
typedef unsigned int u32;

// ws layout (bytes):
//   histA  [0, 16384)          4096 u32  (key bits 31:20)
//   histB  [16384, 32768)      4096 u32  (key bits 19:8, prefix-filtered)
//   state  [32768, 32800)      8 u32: 0=b0 1=K1 2=b1 3=K2 4=cand counter
//   -- memset zero region: [0, 32800) --
//   keys   [65536, 1065536)    250000 u32
//   labels [1065536, 2065536)  250000 u32
//   cand   [2065536, +CAP*8)   u64 keys (score_bits<<32 | ~anchor)

// ---- Kernel 1: per-anchor max/argmax over fg classes -> keys, labels,
//      + fused 4096-bin histogram of key bits [31:20].
// One wave per anchor-iteration; block covers 256 anchors.
__global__ void score_reduce(const float* __restrict__ scores,
                             u32* __restrict__ keys, u32* __restrict__ labels,
                             u32* __restrict__ histA) {
  __shared__ u32 lh[NBINS];
  __shared__ u32 kbuf[4][64];
  __shared__ u32 lbuf[4][64];
  int t = threadIdx.x;
  for (int i = t; i < NBINS; i += 256) lh[i] = 0;
  int wv = t >> 6, lane = t & 63;
  __syncthreads();
  int base = blockIdx.x * 256 + wv * 64;
  for (int it = 0; it < 64; ++it) {
    int a = base + it;
    float v = -1.f; int c = 0;
    if (a < N_ANCH) {
      const float* row = scores + (long long)a * N_CLS;
      v = row[1 + lane]; c = lane;
      if (lane < 16) {
        float v2 = row[65 + lane];
        if (v2 > v) { v = v2; c = 64 + lane; }   // tie -> first occurrence
      }
    }
    for (int off = 32; off > 0; off >>= 1) {
      float ov = __shfl_down(v, off, 64);
      int   oc = __shfl_down(c, off, 64);
      if (ov > v || (ov == v && oc < c)) { v = ov; c = oc; }
    }
    if (lane == 0 && a < N_ANCH) {
      u32 kb = __float_as_uint(v);
      kbuf[wv][it] = kb;
      lbuf[wv][it] = (u32)c;
      atomicAdd(&lh[kb >> 20], 1u);
    }
  }
  __syncthreads();
  int a = blockIdx.x * 256 + wv * 64 + lane;
  if (a < N_ANCH) {
    keys[a] = kbuf[wv][lane];     // coalesced
    labels[a] = lbuf[wv][lane];   // coalesced
  }
  for (int i = t; i < NBINS; i += 256)
    if (lh[i]) atomicAdd(&histA[i], lh[i]);  // few occupied bins per block
}

// ---- Suffix-scan over 4096-bin histogram: smallest bin b with
// count(>= b) >= K; outputs b and K' = K - count(> b).
__global__ void scan_hist(const u32* __restrict__ hist,
                          const u32* __restrict__ Kin, u32 Kimm,
                          u32* __restrict__ b_out, u32* __restrict__ K_out) {
  __shared__ u32 csum[256];
  __shared__ u32 suf[256];
  int t = threadIdx.x;
  const int chunk = NBINS >> 8;   // 16
  int base = t * chunk;
  u32 s = 0;
  for (int i = 0; i < chunk; ++i) s += hist[base + i];
  csum[t] = s;
  __syncthreads();
  if (t == 0) {
    u32 acc = 0;
    for (int i = 255; i >= 0; --i) { suf[i] = acc; acc += csum[i]; }
  }
  __syncthreads();
  u32 K = Kin ? *Kin : Kimm;
  if (suf[t] < K && suf[t] + csum[t] >= K) {   // unique owner thread
    u32 acc = suf[t];
    for (int i = chunk - 1; i >= 0; --i) {
      u32 c = hist[base + i];
      if (acc + c >= K) { *b_out = (u32)(base + i); *K_out = K - acc; break; }
      acc += c;
    }
  }
}

// ---- Pass 2 histogram: bits [19:8] among keys whose bits [31:20] == b0
__global__ void hist_b(const u32* __restrict__ keys, const u32* __restrict__ state,
                       u32* __restrict__ histB) {
  __shared__ u32 lh[NBINS];
  int t = threadIdx.x;
  for (int i = t; i < NBINS; i += 256) lh[i] = 0;
  __syncthreads();
  int i = blockIdx.x * 256 + t;
  u32 b0 = state[0];
  if (i < N_ANCH) {
    u32 k = keys[i];
    if ((k >> 20) == b0) atomicAdd(&lh[(k >> 8) & 0xFFFu], 1u);
  }
  __syncthreads();
  for (int j = t; j < NBINS; j += 256)
    if (lh[j]) atomicAdd(&histB[j], lh[j]);
}

// ---- Compact keys >= threshold (low 8 bits truncated) into candidates
__global__ void compact(const u32* __restrict__ keys, u32* __restrict__ state,
                        u64* __restrict__ cand) {
  int i = blockIdx.x * 256 + threadIdx.x;
  if (i >= N_ANCH) return;
  u32 T = (state[0] << 20) | (state[2] << 8);
  u32 k = keys[i];
  if (k >= T) {
    u32 pos = atomicAdd(&state[4], 1u);
    if (pos < CAP) cand[pos] = ((u64)k << 32) | (u32)(~(u32)i);
  }
}

// ---- Final: exact rank of candidates -> ordered top-200, greedy NMS, outputs
__global__ void final_nms(const u64* __restrict__ cand_g, const u32* __restrict__ state,
                          const u32* __restrict__ labels, const float* __restrict__ boxes,
                          const int* __restrict__ wptr, const int* __restrict__ hptr,
                          float* __restrict__ out) {
  __shared__ u64 cand[CAP];
  __shared__ u32 s_anchor[K_TOP];
  __shared__ float s_score[K_TOP];
  __shared__ float sx1[K_TOP], sy1[K_TOP], sx2[K_TOP], sy2[K_TOP], sarea[K_TOP];
  __shared__ float red[256];
  __shared__ u64 rows[K_TOP * 4];
  __shared__ u64 keepw[4];
  int t = threadIdx.x;
  int M = (int)state[4]; if (M > CAP) M = CAP;
  for (int i = t; i < M; i += 256) cand[i] = cand_g[i];
  if (t < K_TOP) { s_anchor[t] = 0u; s_score[t] = 0.f; }
  __syncthreads();
  // exact rank: keys unique (low bits ~anchor) -> rank<200 == top-200 in order
  for (int i = t; i < M; i += 256) {
    u64 k = cand[i]; int r = 0;
    for (int j = 0; j < M; ++j) r += (cand[j] > k) ? 1 : 0;
    if (r < K_TOP) {
      s_anchor[r] = ~(u32)(k & 0xFFFFFFFFULL);
      s_score[r] = __uint_as_float((u32)(k >> 32));
    }
  }
  __syncthreads();
  float score = 0.f, b0 = 0.f, b1 = 0.f, b2 = 0.f, b3 = 0.f;
  int lab = 0;
  if (t < K_TOP) {
    score = s_score[t];
    u32 a = s_anchor[t];
    float4 bb = *(const float4*)(boxes + (long long)a * 4);
    b0 = bb.x; b1 = bb.y; b2 = bb.z; b3 = bb.w;
    lab = (int)labels[a];
  }
  // max_coord over ALL 200 boxes (reference does not condition on valid)
  red[t] = (t < K_TOP) ? fmaxf(fmaxf(b0, b1), fmaxf(b2, b3)) : -1e30f;
  __syncthreads();
  for (int s = 128; s > 0; s >>= 1) {
    if (t < s) red[t] = fmaxf(red[t], red[t + s]);
    __syncthreads();
  }
  float max_coord = red[0];
  float x1 = 0.f, y1 = 0.f, x2 = 0.f, y2 = 0.f, area = 0.f;
  if (t < K_TOP) {
    float off = (float)lab * (max_coord + 1.0f);
    x1 = b0 + off; y1 = b1 + off; x2 = b2 + off; y2 = b3 + off;
    sx1[t] = x1; sy1[t] = y1; sx2[t] = x2; sy2[t] = y2;
    area = fmaxf(x2 - x1, 0.f) * fmaxf(y2 - y1, 0.f);   // shifted-coord area
    sarea[t] = area;
  }
  __syncthreads();
  // rows build: thread t owns j=t; loop i with LDS broadcast reads
  int wv = t >> 6, l = t & 63;
  for (int i = 0; i < K_TOP; ++i) {
    bool pred = false;
    if (t < K_TOP && t > i) {
      float xx1 = fmaxf(sx1[i], x1);
      float yy1 = fmaxf(sy1[i], y1);
      float xx2 = fminf(sx2[i], x2);
      float yy2 = fminf(sy2[i], y2);
      float inter = fmaxf(xx2 - xx1, 0.f) * fmaxf(yy2 - yy1, 0.f);
      float uni = sarea[i] + area - inter;
      float iou = inter / fmaxf(uni, 1e-12f);
      pred = iou > IOU_THR;
    }
    u64 m = __ballot(pred);
    if (l == 0) rows[i * 4 + wv] = m;
  }
  bool valid = (t < K_TOP) && (score > SCORE_THR);
  u64 vm = __ballot(valid);
  if (l == 0) keepw[wv] = vm;
  __syncthreads();
  if (t == 0) {
    u64 K0 = keepw[0], K1 = keepw[1], K2 = keepw[2], K3 = keepw[3];
    for (int i = 0; i < K_TOP; i++) {
      u64 word = (i < 64) ? K0 : (i < 128) ? K1 : (i < 192) ? K2 : K3;
      if ((word >> (i & 63)) & 1ULL) {
        K0 &= ~rows[i * 4 + 0];
        K1 &= ~rows[i * 4 + 1];
        K2 &= ~rows[i * 4 + 2];
        K3 &= ~rows[i * 4 + 3];
      }
    }
    keepw[0] = K0; keepw[1] = K1; keepw[2] = K2; keepw[3] = K3;
  }
  __syncthreads();
  if (t < K_TOP) {
    bool keep = (keepw[t >> 6] >> (t & 63)) & 1ULL;
    float sw = (float)(*wptr), sh = (float)(*hptr);
    out[t * 4 + 0] = keep ? b0 * sw : 0.f;
    out[t * 4 + 1] = keep ? b1 * sh : 0.f;
    out[t * 4 + 2] = keep ? b2 * sw : 0.f;
    out[t * 4 + 3] = keep ? b3 * sh : 0.f;
    out[4 * K_TOP + t] = keep ? (float)(lab + 1) : 0.f;
    out[5 * K_TOP + t] = keep ? score : 0.f;
  }
}

extern "C" void kernel_launch(void* const* d_in, const int* in_sizes, int n_in,
                              void* d_out, int out_size, void* d_ws, size_t ws_size,
                              hipStream_t stream) {
  const float* scores = (const float*)d_in[0];
  const float* boxes  = (const float*)d_in[1];
  const int* wptr = (const int*)d_in[2];
  const int* hptr = (const int*)d_in[3];
  float* out = (float*)d_out;

  char* ws = (char*)d_ws;
  u32* histA  = (u32*)(ws + 0);
  u32* histB  = (u32*)(ws + 16384);
  u32* state  = (u32*)(ws + 32768);
  u32* keys   = (u32*)(ws + 65536);
  u32* labels = (u32*)(ws + 1065536);
  u64* cand   = (u64*)(ws + 2065536);

  hipMemsetAsync(ws, 0, 32800, stream);

  int blocks = (N_ANCH + 255) / 256;   // 977

  score_reduce<<<blocks, 256, 0, stream>>>(scores, keys, labels, histA);
  scan_hist<<<1, 256, 0, stream>>>(histA, nullptr, K_TOP, &state[0], &state[1]);
  hist_b<<<blocks, 256, 0, stream>>>(keys, state, histB);
  scan_hist<<<1, 256, 0, stream>>>(histB, &state[1], 0, &state[2], &state[3]);
  compact<<<blocks, 256, 0, stream>>>(keys, state, cand);
  final_nms<<<1, 256, 0, stream>>>(cand, state, labels, boxes, wptr, hptr, out);
}